// Round 5
// baseline (442.495 us; speedup 1.0000x reference)
//
#include <hip/hip_runtime.h>
#include <math.h>

#define HDIM 768      // H (hidden) — instance-fixed
#define CH 4          // rows per staged chunk

__device__ __forceinline__ float dot4(const float4 a, const float4 b) {
  return a.x * b.x + a.y * b.y + a.z * b.z + a.w * b.w;
}

__device__ __forceinline__ void async16(const float* g, float* l) {
  __builtin_amdgcn_global_load_lds(
      (const __attribute__((address_space(1))) void*)g,
      (__attribute__((address_space(3))) void*)l, 16, 0, 0);
}

// ---------------- kernel 0: input-width detection (slot writes, no atomics/zeroing) ----
// slots[0..63]: per-block OR of odd words of mask buffer; slots[64..127]: same for smap.
// int64 {small}-valued data has all-zero odd (hi) words; genuine int32 data doesn't.
__global__ __launch_bounds__(256) void detect_slots(const unsigned* __restrict__ mask_w,
                                                    const unsigned* __restrict__ smap_w,
                                                    unsigned* __restrict__ slots,
                                                    int mask_words, int smap_words) {
  __shared__ unsigned red[2];
  const int b = blockIdx.x, tid = threadIdx.x;
  if (tid < 2) red[tid] = 0;
  __syncthreads();
  const int gtid = b * 256 + tid, gsz = gridDim.x * 256;
  unsigned acc = 0;
  for (int i = gtid; i < mask_words / 2; i += gsz) acc |= mask_w[2 * i + 1];
  unsigned acc2 = 0;
  for (int i = gtid; i < smap_words / 2; i += gsz) acc2 |= smap_w[2 * i + 1];
  if (acc)  atomicOr(&red[0], 1u);   // LDS, idempotent value -> deterministic
  if (acc2) atomicOr(&red[1], 1u);
  __syncthreads();
  if (tid == 0) { slots[b] = red[0]; slots[64 + b] = red[1]; }
}

// ---------------- kernel 1: mean over L ----------------
__global__ __launch_bounds__(384) void mean_kernel(const float* __restrict__ hs,
                                                   float* __restrict__ meanb, int L) {
  __shared__ float4 red2[HDIM / 4];
  const int n = blockIdx.x;
  const int tid = threadIdx.x;
  const int half = tid / 192, t = tid % 192;
  const float4* row = reinterpret_cast<const float4*>(hs) + (size_t)n * L * (HDIM / 4);
  float ax = 0.f, ay = 0.f, az = 0.f, aw = 0.f;
  int l = half;
  for (; l + 16 <= L; l += 16) {
    float4 u[8];
#pragma unroll
    for (int i = 0; i < 8; ++i) u[i] = row[(size_t)(l + 2 * i) * (HDIM / 4) + t];
#pragma unroll
    for (int i = 0; i < 8; ++i) { ax += u[i].x; ay += u[i].y; az += u[i].z; aw += u[i].w; }
  }
  for (; l < L; l += 2) {
    float4 u = row[(size_t)l * (HDIM / 4) + t];
    ax += u.x; ay += u.y; az += u.z; aw += u.w;
  }
  if (half == 1) { float4 o; o.x = ax; o.y = ay; o.z = az; o.w = aw; red2[t] = o; }
  __syncthreads();
  if (half == 0) {
    const float inv = 1.0f / (float)L;
    const float4 r = red2[t];
    float4 o;
    o.x = (ax + r.x) * inv; o.y = (ay + r.y) * inv;
    o.z = (az + r.z) * inv; o.w = (aw + r.w) * inv;
    reinterpret_cast<float4*>(meanb + (size_t)n * HDIM)[t] = o;
  }
}

// ---------------- kernel 2: C[M,Nn] = A[M,K] * B[Nn,K]^T + bias ----------------
__global__ __launch_bounds__(256) void gemm_bt(const float* __restrict__ A,
                                               const float* __restrict__ B,
                                               const float* __restrict__ bias,
                                               float* __restrict__ C,
                                               int M, int Nn, int K) {
  __shared__ float As[32][17];
  __shared__ float Bs[64][17];
  const int m0 = blockIdx.x * 32, n0 = blockIdx.y * 64;
  const int idx = threadIdx.x;
  const int lc = idx & 15, lr = idx >> 4;
  const int tc = idx & 15, tr = idx >> 4;
  float c[2][4] = {{0.f,0.f,0.f,0.f},{0.f,0.f,0.f,0.f}};
  for (int k0 = 0; k0 < K; k0 += 16) {
    __syncthreads();
    As[lr][lc]      = A[(size_t)(m0 + lr) * K + k0 + lc];
    As[lr + 16][lc] = A[(size_t)(m0 + lr + 16) * K + k0 + lc];
    Bs[lr][lc]      = B[(size_t)(n0 + lr) * K + k0 + lc];
    Bs[lr + 16][lc] = B[(size_t)(n0 + lr + 16) * K + k0 + lc];
    Bs[lr + 32][lc] = B[(size_t)(n0 + lr + 32) * K + k0 + lc];
    Bs[lr + 48][lc] = B[(size_t)(n0 + lr + 48) * K + k0 + lc];
    __syncthreads();
#pragma unroll
    for (int k = 0; k < 16; ++k) {
      const float a0 = As[tr * 2][k], a1 = As[tr * 2 + 1][k];
      const float b0 = Bs[tc * 4][k], b1 = Bs[tc * 4 + 1][k];
      const float b2 = Bs[tc * 4 + 2][k], b3 = Bs[tc * 4 + 3][k];
      c[0][0] += a0 * b0; c[0][1] += a0 * b1; c[0][2] += a0 * b2; c[0][3] += a0 * b3;
      c[1][0] += a1 * b0; c[1][1] += a1 * b1; c[1][2] += a1 * b2; c[1][3] += a1 * b3;
    }
  }
#pragma unroll
  for (int j = 0; j < 4; ++j) {
    const float bv = bias ? bias[n0 + tc * 4 + j] : 0.f;
    C[(size_t)(m0 + tr * 2) * Nn + n0 + tc * 4 + j]     = c[0][j] + bv;
    C[(size_t)(m0 + tr * 2 + 1) * Nn + n0 + tc * 4 + j] = c[1][j] + bv;
  }
}

// ---------------- kernel 3: C[M,Nn] = A[M,K] * B[K,Nn] ----------------
__global__ __launch_bounds__(256) void gemm_bn(const float* __restrict__ A,
                                               const float* __restrict__ B,
                                               float* __restrict__ C,
                                               int M, int Nn, int K) {
  __shared__ float As[32][17];
  __shared__ float Bs[16][65];
  const int m0 = blockIdx.x * 32, n0 = blockIdx.y * 64;
  const int idx = threadIdx.x;
  const int lc = idx & 15, lr = idx >> 4;
  const int bc = idx & 63, br = idx >> 6;
  const int tc = idx & 15, tr = idx >> 4;
  float c[2][4] = {{0.f,0.f,0.f,0.f},{0.f,0.f,0.f,0.f}};
  for (int k0 = 0; k0 < K; k0 += 16) {
    __syncthreads();
    As[lr][lc]      = A[(size_t)(m0 + lr) * K + k0 + lc];
    As[lr + 16][lc] = A[(size_t)(m0 + lr + 16) * K + k0 + lc];
    Bs[br][bc]      = B[(size_t)(k0 + br) * Nn + n0 + bc];
    Bs[br + 4][bc]  = B[(size_t)(k0 + br + 4) * Nn + n0 + bc];
    Bs[br + 8][bc]  = B[(size_t)(k0 + br + 8) * Nn + n0 + bc];
    Bs[br + 12][bc] = B[(size_t)(k0 + br + 12) * Nn + n0 + bc];
    __syncthreads();
#pragma unroll
    for (int k = 0; k < 16; ++k) {
      const float a0 = As[tr * 2][k], a1 = As[tr * 2 + 1][k];
      const float b0 = Bs[k][tc * 4], b1 = Bs[k][tc * 4 + 1];
      const float b2 = Bs[k][tc * 4 + 2], b3 = Bs[k][tc * 4 + 3];
      c[0][0] += a0 * b0; c[0][1] += a0 * b1; c[0][2] += a0 * b2; c[0][3] += a0 * b3;
      c[1][0] += a1 * b0; c[1][1] += a1 * b1; c[1][2] += a1 * b2; c[1][3] += a1 * b3;
    }
  }
#pragma unroll
  for (int j = 0; j < 4; ++j) {
    C[(size_t)(m0 + tr * 2) * Nn + n0 + tc * 4 + j]     = c[0][j];
    C[(size_t)(m0 + tr * 2 + 1) * Nn + n0 + tc * 4 + j] = c[1][j];
  }
}

// ---------------- kernel 4: scores + online softmax + weighted pool (partials) -------
// Grid 2N blocks = (n, L-half), reversed n for L3 reuse. hs DMA'd to LDS via
// global_load_lds, double-buffered; DMA for chunk c+1 stays in flight across
// compute of chunk c (raw s_barrier — no vmcnt(0) drain). Per-thread state is
// 3 accumulator floats; online softmax is block-uniform via LDS scores.
__global__ __launch_bounds__(256) void attnpool(const float* __restrict__ hs,
                                                const unsigned* __restrict__ mask_w,
                                                const float* __restrict__ v,
                                                const unsigned* __restrict__ slots,
                                                float* __restrict__ acc_out,
                                                float* __restrict__ ms_out, int L) {
  __shared__ float buf[2][CH * HDIM];   // 2 x 12 KB
  __shared__ int   mrow[256];
  __shared__ float sc[CH];
  __shared__ unsigned mflag_sh;
  const int bid = blockIdx.x;
  const int n = (gridDim.x / 2 - 1) - (bid >> 1);   // reversed for L3 reuse
  const int half = bid & 1;
  const int tid = threadIdx.x, w = tid >> 6, lane = tid & 63;
  const int Lh = L / 2, r0 = half * Lh;

  if (tid == 0) {
    unsigned f = 0;
    for (int i = 0; i < 64; ++i) f |= slots[i];
    mflag_sh = f;
  }
  __syncthreads();
  const int mask_is_i32 = (mflag_sh != 0);
  for (int t = tid; t < Lh; t += 256) {
    const size_t idx = (size_t)n * L + r0 + t;
    mrow[t] = (int)(mask_is_i32 ? mask_w[idx] : mask_w[2 * idx]);
  }

  const float4* v4 = reinterpret_cast<const float4*>(v + (size_t)n * HDIM);
  const float4 vf0 = v4[lane], vf1 = v4[64 + lane], vf2 = v4[128 + lane];
  const float* base = hs + ((size_t)n * L + r0) * HDIM;
  const float scale = 1.0f / sqrtf((float)HDIM);

  // DMA one chunk (CH rows = 12 KB): 3 sweeps of 256 lanes x 16 B.
  auto stage = [&](int b, int c) {
    const float* src = base + (size_t)c * (CH * HDIM);
    float* dst = buf[b];
#pragma unroll
    for (int i = 0; i < 3; ++i) {
      const int off = i * 1024 + w * 256;          // wave-uniform LDS offset
      async16(src + off + lane * 4, dst + off);    // HW writes lds base + lane*16
    }
  };

  stage(0, 0);
  float m = -3.0e38f, ssum = 0.f, a0 = 0.f, a1 = 0.f, a2 = 0.f;
  const int nch = Lh / CH;   // 64

  for (int c = 0; c < nch; ++c) {
    // own DMA for chunk c done (only my asyncs are in flight here); then barrier:
    // everyone's chunk-c DMA done AND everyone finished reading buf[(c+1)&1].
    asm volatile("s_waitcnt vmcnt(0) lgkmcnt(0)" ::: "memory");
    __builtin_amdgcn_s_barrier();
    if (c + 1 < nch) stage((c + 1) & 1, c + 1);    // in flight across this chunk's compute
    const float* cb = buf[c & 1];

    // ---- score: wave w computes row w ----
    {
      const float4* rp = reinterpret_cast<const float4*>(cb + w * HDIM);
      float p = dot4(rp[lane], vf0) + dot4(rp[64 + lane], vf1) + dot4(rp[128 + lane], vf2);
#pragma unroll
      for (int off = 32; off > 0; off >>= 1) p += __shfl_xor(p, off, 64);
      float s = (mrow[c * CH + w] == 0) ? -1e9f : p * scale;
      if (lane == 0) sc[w] = s;
    }
    asm volatile("s_waitcnt lgkmcnt(0)" ::: "memory");
    __builtin_amdgcn_s_barrier();                  // sc visible; DMA stays in flight

    // ---- block-uniform online softmax + per-thread 3-column accumulate ----
    const float s0 = sc[0], s1 = sc[1], s2 = sc[2], s3 = sc[3];
    const float mc = fmaxf(fmaxf(s0, s1), fmaxf(s2, s3));
    if (mc > m) {
      const float f = __expf(m - mc);
      ssum *= f; a0 *= f; a1 *= f; a2 *= f;
      m = mc;
    }
    const float p0 = __expf(s0 - m), p1 = __expf(s1 - m);
    const float p2 = __expf(s2 - m), p3 = __expf(s3 - m);
    ssum += p0 + p1 + p2 + p3;
    a0 += p0 * cb[tid]             + p1 * cb[HDIM + tid]
        + p2 * cb[2 * HDIM + tid]  + p3 * cb[3 * HDIM + tid];
    a1 += p0 * cb[256 + tid]            + p1 * cb[HDIM + 256 + tid]
        + p2 * cb[2 * HDIM + 256 + tid] + p3 * cb[3 * HDIM + 256 + tid];
    a2 += p0 * cb[512 + tid]            + p1 * cb[HDIM + 512 + tid]
        + p2 * cb[2 * HDIM + 512 + tid] + p3 * cb[3 * HDIM + 512 + tid];
    // next iteration's top barrier protects cb from re-staging
  }

  const int pidx = n * 2 + half;
  acc_out[(size_t)pidx * HDIM + tid]       = a0;
  acc_out[(size_t)pidx * HDIM + 256 + tid] = a1;
  acc_out[(size_t)pidx * HDIM + 512 + tid] = a2;
  if (tid == 0) { ms_out[pidx * 2] = m; ms_out[pidx * 2 + 1] = ssum; }
}

// ---------------- kernel 5: merge halves + segment mean ----------------
__global__ __launch_bounds__(256) void merge_segmean(const float* __restrict__ acc,
                                                     const float* __restrict__ ms,
                                                     const void* __restrict__ smap,
                                                     const unsigned* __restrict__ slots_s,
                                                     float* __restrict__ out, int N) {
  __shared__ unsigned fsh;
  const int t = blockIdx.x, tid = threadIdx.x;
  const int col = blockIdx.y * 256 + tid;
  if (tid == 0) {
    unsigned f = 0;
    for (int i = 0; i < 64; ++i) f |= slots_s[i];
    fsh = f;
  }
  __syncthreads();
  const int smap_is_i32 = (fsh != 0);
  float a = 0.f;
  int cnt = 0;
  for (int i = 0; i < N; ++i) {
    const int s = smap_is_i32 ? ((const int*)smap)[i]
                              : (int)((const long long*)smap)[i];
    if (s != t) continue;
    const float m0 = ms[(i * 2) * 2],     q0 = ms[(i * 2) * 2 + 1];
    const float m1 = ms[(i * 2 + 1) * 2], q1 = ms[(i * 2 + 1) * 2 + 1];
    const float M = fmaxf(m0, m1);
    const float f0 = __expf(m0 - M), f1 = __expf(m1 - M);
    const float S = q0 * f0 + q1 * f1;
    const float o = (acc[(size_t)(i * 2) * HDIM + col] * f0 +
                     acc[(size_t)(i * 2 + 1) * HDIM + col] * f1) / S;
    a += o; ++cnt;
  }
  out[(size_t)t * HDIM + col] = a / (float)(cnt > 0 ? cnt : 1);
}

extern "C" void kernel_launch(void* const* d_in, const int* in_sizes, int n_in,
                              void* d_out, int out_size, void* d_ws, size_t ws_size,
                              hipStream_t stream) {
  const float*    hs     = (const float*)d_in[0];
  const unsigned* mask_w = (const unsigned*)d_in[1];
  const void*     smap   = d_in[2];
  const float*    Wq     = (const float*)d_in[3];
  const float*    bq     = (const float*)d_in[4];
  const float*    Wk     = (const float*)d_in[5];
  // d_in[6] = bk: dead (per-row constant on scores -> softmax-invariant)

  const int N = in_sizes[2];           // 512
  const int L = in_sizes[1] / N;       // 512
  const int H = in_sizes[4];           // 768 (== HDIM)
  const int T = out_size / H;          // 32
  const size_t NH = (size_t)N * H;

  float* meanb = (float*)d_ws;               // [N,H]
  float* q     = meanb + NH;                 // [N,H]
  float* v     = q + NH;                     // [N,H]
  float* acc   = v + NH;                     // [2N,H] block partial accumulators
  float* ms    = acc + 2 * NH;               // [2N,2] block partial (m, ssum)
  unsigned* slots = (unsigned*)(ms + 4 * N); // [128]
  (void)ws_size; (void)n_in;

  detect_slots<<<64, 256, 0, stream>>>(mask_w, (const unsigned*)smap, slots, N * L, N);
  mean_kernel<<<N, 384, 0, stream>>>(hs, meanb, L);
  gemm_bt<<<dim3(N / 32, H / 64), 256, 0, stream>>>(meanb, Wq, bq, q, N, H, H);
  gemm_bn<<<dim3(N / 32, H / 64), 256, 0, stream>>>(q, Wk, v, N, H, H);
  attnpool<<<2 * N, 256, 0, stream>>>(hs, mask_w, v, slots, acc, ms, L);
  merge_segmean<<<dim3(T, 3), 256, 0, stream>>>(acc, ms, smap, slots + 64, (float*)d_out, N);
}

// Round 6
// 419.731 us; speedup vs baseline: 1.0542x; 1.0542x over previous
//
#include <hip/hip_runtime.h>
#include <math.h>

#define HDIM 768
#define NG   192        // HDIM/4 float4 groups
#define LMAX 512

__device__ __forceinline__ float dot4(const float4 a, const float4 b) {
  return a.x * b.x + a.y * b.y + a.z * b.z + a.w * b.w;
}
__device__ __forceinline__ void fma4(float4& a, const float s, const float4 b) {
  a.x += s * b.x; a.y += s * b.y; a.z += s * b.z; a.w += s * b.w;
}
__device__ __forceinline__ void scale4(float4& a, const float s) {
  a.x *= s; a.y *= s; a.z *= s; a.w *= s;
}

// ---------------- kernel 0: input-width detection (slot writes) ----------------
// slots[0..63]: OR of odd 32-bit words of mask buffer (int64 layout -> 0)
// slots[64..127]: same for sample_map.
__global__ __launch_bounds__(256) void detect_slots(const unsigned* __restrict__ mask_w,
                                                    const unsigned* __restrict__ smap_w,
                                                    unsigned* __restrict__ slots,
                                                    int mask_words, int smap_words) {
  __shared__ unsigned red[2];
  const int b = blockIdx.x, tid = threadIdx.x;
  if (tid < 2) red[tid] = 0;
  __syncthreads();
  const int gtid = b * 256 + tid, gsz = gridDim.x * 256;
  unsigned acc = 0;
  for (int i = gtid; i < mask_words / 2; i += gsz) acc |= mask_w[2 * i + 1];
  unsigned acc2 = 0;
  for (int i = gtid; i < smap_words / 2; i += gsz) acc2 |= smap_w[2 * i + 1];
  if (acc)  atomicOr(&red[0], 1u);
  if (acc2) atomicOr(&red[1], 1u);
  __syncthreads();
  if (tid == 0) { slots[b] = red[0]; slots[64 + b] = red[1]; }
}

// ---------------- kernel 1: Wc = Wq^T * Wk, c0 = bq * Wk ----------------
// Wc[i][j] = sum_o Wq[o][i] * Wk[o][j];  c0[j] = sum_o bq[o] * Wk[o][j].
__global__ __launch_bounds__(256) void prep_wc(const float* __restrict__ Wq,
                                               const float* __restrict__ Wk,
                                               const float* __restrict__ bq,
                                               float* __restrict__ Wc,
                                               float* __restrict__ c0, int H) {
  __shared__ float As[16][33];
  __shared__ float Bs[16][65];
  __shared__ float bqs[16];
  const int i0 = blockIdx.x * 32, j0 = blockIdx.y * 64;
  const int idx = threadIdx.x;
  const int li = idx & 31, lk = idx >> 5;    // A loads: 2 per thread
  const int lj = idx & 63, lk2 = idx >> 6;   // B loads: 4 per thread
  const int tc = idx & 15, tr = idx >> 4;
  float c[2][4] = {{0.f,0.f,0.f,0.f},{0.f,0.f,0.f,0.f}};
  float cb[4] = {0.f,0.f,0.f,0.f};
  const bool bias_lane = (blockIdx.x == 0) && (tr == 0);
  for (int o0 = 0; o0 < H; o0 += 16) {
    __syncthreads();
    As[lk][li]       = Wq[(size_t)(o0 + lk) * H + i0 + li];
    As[lk + 8][li]   = Wq[(size_t)(o0 + lk + 8) * H + i0 + li];
    Bs[lk2][lj]      = Wk[(size_t)(o0 + lk2) * H + j0 + lj];
    Bs[lk2 + 4][lj]  = Wk[(size_t)(o0 + lk2 + 4) * H + j0 + lj];
    Bs[lk2 + 8][lj]  = Wk[(size_t)(o0 + lk2 + 8) * H + j0 + lj];
    Bs[lk2 + 12][lj] = Wk[(size_t)(o0 + lk2 + 12) * H + j0 + lj];
    if (idx < 16) bqs[idx] = bq[o0 + idx];
    __syncthreads();
#pragma unroll
    for (int k = 0; k < 16; ++k) {
      const float a0 = As[k][tr * 2], a1 = As[k][tr * 2 + 1];
      const float b0 = Bs[k][tc * 4],     b1 = Bs[k][tc * 4 + 1];
      const float b2 = Bs[k][tc * 4 + 2], b3 = Bs[k][tc * 4 + 3];
      c[0][0] += a0 * b0; c[0][1] += a0 * b1; c[0][2] += a0 * b2; c[0][3] += a0 * b3;
      c[1][0] += a1 * b0; c[1][1] += a1 * b1; c[1][2] += a1 * b2; c[1][3] += a1 * b3;
      if (bias_lane) {
        const float bv = bqs[k];
        cb[0] += bv * b0; cb[1] += bv * b1; cb[2] += bv * b2; cb[3] += bv * b3;
      }
    }
  }
#pragma unroll
  for (int j = 0; j < 4; ++j) {
    Wc[(size_t)(i0 + tr * 2) * H + j0 + tc * 4 + j]     = c[0][j];
    Wc[(size_t)(i0 + tr * 2 + 1) * H + j0 + tc * 4 + j] = c[1][j];
  }
  if (bias_lane) {
#pragma unroll
    for (int j = 0; j < 4; ++j) c0[j0 + tc * 4 + j] = cb[j];
  }
}

// ---------------- kernel 2: fused mean -> GEMV -> scores/softmax/pool ----------------
// One block per n, 384 threads (6 waves).
// Pass 1 streams hs[n] FORWARD (mean). GEMV v = mean*Wc + c0 (Wc from L2).
// Pass 2 streams hs[n] BACKWARD (waves interleaved descending) so its first
// ~30% of reads hit the L3-resident tail of pass 1. Wave-local online softmax
// with defer-rescale; 6-way split-softmax merge at the end (one barrier).
__global__ __launch_bounds__(384) void fused(const float* __restrict__ hs,
                                             const unsigned* __restrict__ mask_w,
                                             const float* __restrict__ Wc,
                                             const float* __restrict__ c0,
                                             const unsigned* __restrict__ slots,
                                             float* __restrict__ pooled, int L) {
  __shared__ float4 red2[NG];        // 3 KB pass-1 cross-half reduce
  __shared__ float4 meanv4[NG];      // 3 KB mean vector
  __shared__ float4 vv4[NG];         // 3 KB v vector
  __shared__ float4 redv4[6][NG];    // 18 KB split-softmax merge
  __shared__ float mw[6], sw[6];
  __shared__ int   mrow[LMAX];       // 2 KB
  __shared__ unsigned mfl;
  const int n = blockIdx.x, tid = threadIdx.x;
  const int w = tid >> 6, lane = tid & 63;

  if (tid == 0) mfl = 0u;
  __syncthreads();
  if (tid < 64 && slots[tid]) atomicOr(&mfl, 1u);

  // ---- pass 1: mean over L (forward stream) ----
  const int half = tid / NG, t = tid - half * NG;
  const float4* hb = reinterpret_cast<const float4*>(hs) + (size_t)n * L * NG;
  float ax = 0.f, ay = 0.f, az = 0.f, aw = 0.f;
  int l = half;
  for (; l + 16 <= L; l += 16) {
    float4 u[8];
#pragma unroll
    for (int i = 0; i < 8; ++i) u[i] = hb[(size_t)(l + 2 * i) * NG + t];
#pragma unroll
    for (int i = 0; i < 8; ++i) { ax += u[i].x; ay += u[i].y; az += u[i].z; aw += u[i].w; }
  }
  for (; l < L; l += 2) {
    float4 u = hb[(size_t)l * NG + t];
    ax += u.x; ay += u.y; az += u.z; aw += u.w;
  }
  if (half == 1) { float4 o; o.x = ax; o.y = ay; o.z = az; o.w = aw; red2[t] = o; }
  __syncthreads();   // red2 ready; mfl atomic ops ordered

  if (half == 0) {
    const float inv = 1.0f / (float)L;
    const float4 r = red2[t];
    float4 o;
    o.x = (ax + r.x) * inv; o.y = (ay + r.y) * inv;
    o.z = (az + r.z) * inv; o.w = (aw + r.w) * inv;
    meanv4[t] = o;
  }
  const int mask_is_i32 = (mfl != 0);
  for (int tt = tid; tt < L; tt += 384) {
    const size_t idx = (size_t)n * L + tt;
    mrow[tt] = (int)(mask_is_i32 ? mask_w[idx] : mask_w[2 * idx]);
  }
  __syncthreads();   // meanv, mrow ready

  // ---- GEMV: v = mean * Wc + c0 (thread owns cols tid, tid+384) ----
  {
    const int c1 = tid, c2 = tid + 384;
    float acc1 = 0.f, acc2 = 0.f;
    const float* wp = Wc;
    for (int o = 0; o < HDIM; o += 4) {
      const float4 mv = meanv4[o >> 2];
      acc1 += mv.x * wp[c1] + mv.y * wp[HDIM + c1] + mv.z * wp[2 * HDIM + c1] + mv.w * wp[3 * HDIM + c1];
      acc2 += mv.x * wp[c2] + mv.y * wp[HDIM + c2] + mv.z * wp[2 * HDIM + c2] + mv.w * wp[3 * HDIM + c2];
      wp += 4 * HDIM;
    }
    ((float*)vv4)[c1] = acc1 + c0[c1];
    ((float*)vv4)[c2] = acc2 + c0[c2];
  }
  __syncthreads();   // vv ready

  // ---- pass 2: descending interleaved rows, wave-local online softmax ----
  const float4 vf0 = vv4[lane], vf1 = vv4[64 + lane], vf2 = vv4[128 + lane];
  const float scale = 1.0f / sqrtf((float)HDIM);
  const int cnt = (L - 1 - w) / 6 + 1;      // rows this wave owns (85/86)
  float m = -3.0e38f, ss = 0.f;
  float4 A0 = {0,0,0,0}, A1 = {0,0,0,0}, A2 = {0,0,0,0};
  float4 xa[2][3], xb[2][3];

  auto ld = [&](float4 (&X)[2][3], int j) {
#pragma unroll
    for (int u = 0; u < 2; ++u) {
      const int jj = j + u;
      const int rr = (jj < cnt) ? (L - 1 - 6 * jj - w) : 0;   // safe row for pads
      const float4* rp = hb + (size_t)rr * NG;
      X[u][0] = rp[lane]; X[u][1] = rp[64 + lane]; X[u][2] = rp[128 + lane];
    }
  };
  auto pr = [&](float4 (&X)[2][3], int j) {
    float s[2]; bool val[2];
#pragma unroll
    for (int u = 0; u < 2; ++u) {
      const int jj = j + u;
      val[u] = (jj < cnt);
      const int r = L - 1 - 6 * jj - w;
      float p = dot4(X[u][0], vf0) + dot4(X[u][1], vf1) + dot4(X[u][2], vf2);
#pragma unroll
      for (int off = 32; off > 0; off >>= 1) p += __shfl_xor(p, off, 64);
      s[u] = (!val[u] || mrow[r & (LMAX - 1)] == 0) ? -1e9f : p * scale;
    }
    const float mc = fmaxf(s[0], s[1]);
    if (mc > m) {   // defer-rescale: wave-uniform, skipped when max doesn't grow
      const float f = __expf(m - mc);
      ss *= f; scale4(A0, f); scale4(A1, f); scale4(A2, f);
      m = mc;
    }
#pragma unroll
    for (int u = 0; u < 2; ++u) {
      const float pq = val[u] ? __expf(s[u] - m) : 0.f;
      ss += pq;
      fma4(A0, pq, X[u][0]); fma4(A1, pq, X[u][1]); fma4(A2, pq, X[u][2]);
    }
  };

  ld(xa, 0);
  for (int j = 0; j < 88; j += 4) {     // JMAX=88 >= max cnt 86, uniform
    ld(xb, j + 2);
    pr(xa, j);
    if (j + 4 < 88) ld(xa, j + 4);
    pr(xb, j + 2);
  }

  // ---- 6-way split-softmax merge ----
  if (lane == 0) { mw[w] = m; sw[w] = ss; }
  redv4[w][lane]       = A0;
  redv4[w][64 + lane]  = A1;
  redv4[w][128 + lane] = A2;
  __syncthreads();
  float M = mw[0];
#pragma unroll
  for (int j = 1; j < 6; ++j) M = fmaxf(M, mw[j]);
  float f[6], S = 0.f;
#pragma unroll
  for (int j = 0; j < 6; ++j) { f[j] = __expf(mw[j] - M); S += sw[j] * f[j]; }
  const float invS = 1.0f / S;
  const float* redp = (const float*)redv4;
#pragma unroll
  for (int part = 0; part < 2; ++part) {
    const int col = part * 384 + tid;
    float o = 0.f;
#pragma unroll
    for (int j = 0; j < 6; ++j) o += redp[j * HDIM + col] * f[j];
    pooled[(size_t)n * HDIM + col] = o * invS;
  }
}

// ---------------- kernel 3: segment mean ----------------
__global__ __launch_bounds__(256) void segmean(const float* __restrict__ pooled,
                                               const void* __restrict__ smap,
                                               const unsigned* __restrict__ slots_s,
                                               float* __restrict__ out, int N) {
  __shared__ unsigned fsh;
  const int t = blockIdx.x, tid = threadIdx.x;
  const int col = blockIdx.y * 256 + tid;
  if (tid == 0) {
    unsigned f = 0;
    for (int i = 0; i < 64; ++i) f |= slots_s[i];
    fsh = f;
  }
  __syncthreads();
  const int smap_is_i32 = (fsh != 0);
  float a = 0.f;
  int cnt = 0;
  for (int i = 0; i < N; ++i) {
    const int s = smap_is_i32 ? ((const int*)smap)[i]
                              : (int)((const long long*)smap)[i];
    if (s == t) { a += pooled[(size_t)i * HDIM + col]; ++cnt; }
  }
  out[(size_t)t * HDIM + col] = a / (float)(cnt > 0 ? cnt : 1);
}

extern "C" void kernel_launch(void* const* d_in, const int* in_sizes, int n_in,
                              void* d_out, int out_size, void* d_ws, size_t ws_size,
                              hipStream_t stream) {
  const float*    hs     = (const float*)d_in[0];
  const unsigned* mask_w = (const unsigned*)d_in[1];
  const void*     smap   = d_in[2];
  const float*    Wq     = (const float*)d_in[3];
  const float*    bq     = (const float*)d_in[4];
  const float*    Wk     = (const float*)d_in[5];
  // d_in[6] = bk: dead (adds per-row constant to scores -> softmax-invariant)

  const int N = in_sizes[2];           // 512
  const int L = in_sizes[1] / N;       // 512
  const int H = in_sizes[4];           // 768 (== HDIM)
  const int T = out_size / H;          // 32

  float* Wc     = (float*)d_ws;                    // [H,H]
  float* c0     = Wc + (size_t)H * H;              // [H]
  float* pooled = c0 + H;                          // [N,H]
  unsigned* slots = (unsigned*)(pooled + (size_t)N * H);  // [128]
  (void)ws_size; (void)n_in;

  detect_slots<<<64, 256, 0, stream>>>(mask_w, (const unsigned*)smap, slots, N * L, N);
  prep_wc<<<dim3(H / 32, H / 64), 256, 0, stream>>>(Wq, Wk, bq, Wc, c0, H);
  fused<<<N, 384, 0, stream>>>(hs, mask_w, Wc, c0, slots, pooled, L);
  segmean<<<dim3(T, 3), 256, 0, stream>>>(pooled, smap, slots + 64, (float*)d_out, N);
}